// Round 1
// baseline (638.751 us; speedup 1.0000x reference)
//
#include <hip/hip_runtime.h>
#include <hip/hip_bf16.h>

// Problem constants: T=8192, H=1024, D=1024, E=8, 2D=2048, K2=E*D=8192
#define T_DIM 8192
#define H_DIM 1024
#define D_DIM 1024
#define E_DIM 8
#define TWO_D 2048
#define K2 8192

#define ALPHA_C 1.702f
#define LIMIT_C 7.0f

typedef __attribute__((ext_vector_type(8))) short s8v;   // 8 bf16 = 4 VGPRs
typedef __attribute__((ext_vector_type(4))) float f4v;   // MFMA accumulator

__device__ __forceinline__ void g2l16(const void* g, void* l) {
    // async global->LDS, 16B per lane; LDS dest = wave-uniform base + lane*16
    __builtin_amdgcn_global_load_lds((const __attribute__((address_space(1))) void*)g,
                                     (__attribute__((address_space(3))) void*)l, 16, 0, 0);
}

__device__ __forceinline__ unsigned short f2bf(float f) {
    __hip_bfloat16 h = __float2bfloat16(f);
    return __builtin_bit_cast(unsigned short, h);
}

__device__ __forceinline__ float bf2f(unsigned short u) {
    unsigned int x = ((unsigned int)u) << 16;
    return __builtin_bit_cast(float, x);
}

// ---------------- convert kernels ----------------

__global__ void f32_to_bf16_kernel(const float* __restrict__ in,
                                   unsigned short* __restrict__ out, size_t n) {
    size_t i = ((size_t)blockIdx.x * blockDim.x + threadIdx.x) * 4;
    if (i + 3 < n) {
        float4 v = *(const float4*)(in + i);
        ushort4 o;
        o.x = f2bf(v.x); o.y = f2bf(v.y); o.z = f2bf(v.z); o.w = f2bf(v.w);
        *(ushort4*)(out + i) = o;
    }
}

// out[b*obs + remap(c)*ors + r] = bf16(in[b*ibs + r*cols + c]); 32x32 tiles.
// remap==1: c -> (c&~31) + (c&1)*16 + ((c>>1)&15)   (gate/up 16-col deinterleave)
__global__ void transpose_conv_kernel(const float* __restrict__ in,
                                      unsigned short* __restrict__ out,
                                      int cols, size_t ibs, size_t obs, size_t ors,
                                      int remap) {
    __shared__ float t[32][33];
    const int b = blockIdx.z;
    const int c0 = blockIdx.x * 32, r0 = blockIdx.y * 32;
    const int tx = threadIdx.x & 31, ty = threadIdx.x >> 5;  // ty in 0..7
    const float* ip = in + (size_t)b * ibs;
    #pragma unroll
    for (int i = 0; i < 4; ++i)
        t[ty + i * 8][tx] = ip[(size_t)(r0 + ty + i * 8) * cols + c0 + tx];
    __syncthreads();
    unsigned short* op = out + (size_t)b * obs;
    #pragma unroll
    for (int i = 0; i < 4; ++i) {
        int c = c0 + ty + i * 8;
        int nc = remap ? ((c & ~31) + ((c & 1) << 4) + ((c >> 1) & 15)) : c;
        op[(size_t)nc * ors + r0 + tx] = f2bf(t[tx][ty + i * 8]);
    }
}

// out[t][h] += p0 (bf16 partial) + sum_e rw[t][e]*b3[e][h]
__global__ void reduce_bias_kernel(const unsigned short* __restrict__ p0,
                                   const float* __restrict__ rw,
                                   const float* __restrict__ b3,
                                   float* __restrict__ out) {
    const int t = blockIdx.x;
    const int h = threadIdx.x * 4;
    const size_t idx = (size_t)t * H_DIM + h;
    float r[E_DIM];
    #pragma unroll
    for (int e = 0; e < E_DIM; ++e) r[e] = rw[(size_t)t * E_DIM + e];
    float4 v = *(const float4*)(out + idx);
    ushort4 a = *(const ushort4*)(p0 + idx);
    v.x += bf2f(a.x);
    v.y += bf2f(a.y);
    v.z += bf2f(a.z);
    v.w += bf2f(a.w);
    #pragma unroll
    for (int e = 0; e < E_DIM; ++e) {
        float4 bb = *(const float4*)(b3 + (size_t)e * H_DIM + h);
        v.x += r[e] * bb.x; v.y += r[e] * bb.y; v.z += r[e] * bb.z; v.w += r[e] * bb.w;
    }
    *(float4*)(out + idx) = v;
}

// ---------------- 256x256 / BK=64 8-phase counted-vmcnt GEMM core ----------------
// Both operands K-major (A: [M][K], B: [N][K] bf16). 512 threads = 8 waves (2M x 4N),
// per-wave 128x64 output = acc[8][4] 16x16 fragments. LDS 128 KiB:
// As/Bs[2 dbuf][2 k-half][256 rows x 32 elems]. Per tile t (4 phases, one C-half x
// one k-step = 16 MFMA each):
//   q0 (kh0,ch0): stage A(t+1).kh1   q1 (kh0,ch1): stage B(t+1).kh1
//   q2 (kh1,ch0): stage A(t+2).kh0   q3 (kh1,ch1): stage B(t+2).kh0 + vmcnt(4)
// Each stage targets a slot whose last read retired the previous phase (2 raw
// s_barriers per phase). vmcnt(4) covers everything but the q2/q3 stages, i.e.
// tile t+1 is fully landed entering its first read. Tail: at t+2>=NT use vmcnt(0)
// (otherwise tile NT-1's kh1 stages are never covered). Chunk swizzle: phys chunk =
// logical ^ ((row>>1)&3), applied on the global source (linear LDS dest).

#define FEN asm volatile("" ::: "memory")
#define BARR { FEN; __builtin_amdgcn_s_barrier(); FEN; }
#define LGKM0 asm volatile("s_waitcnt lgkmcnt(0)" ::: "memory")

#define LDA4(BUF, KH, CH)                                                        \
  { const short* _p = &As[BUF][KH][aoff + (CH) * 2048];                          \
    a[0] = *(const s8v*)(_p);        a[1] = *(const s8v*)(_p + 512);             \
    a[2] = *(const s8v*)(_p + 1024); a[3] = *(const s8v*)(_p + 1536); }

#define LDB4(BUF, KH)                                                            \
  { const short* _p = &Bs[BUF][KH][boff];                                        \
    b[0] = *(const s8v*)(_p);        b[1] = *(const s8v*)(_p + 512);             \
    b[2] = *(const s8v*)(_p + 1024); b[3] = *(const s8v*)(_p + 1536); }

#define MM16(CH)                                                                 \
  { _Pragma("unroll")                                                            \
    for (int mf = 0; mf < 4; ++mf) {                                             \
      _Pragma("unroll")                                                          \
      for (int nf = 0; nf < 4; ++nf)                                             \
        acc[(CH) * 4 + mf][nf] = __builtin_amdgcn_mfma_f32_16x16x32_bf16(        \
            a[mf], b[nf], acc[(CH) * 4 + mf][nf], 0, 0, 0);                      \
    } }

#define STG(GB, SLOT, KEL)                                                       \
  { const short* _g = (GB) + (size_t)rstage * sK + (KEL) + gco;                  \
    g2l16(_g, &(SLOT)[wave * 1024]);                                             \
    g2l16(_g + 16 * sK, &(SLOT)[wave * 1024 + 512]); }

#define PHASE_TAIL(CH)                                                           \
  BARR; LGKM0;                                                                   \
  __builtin_amdgcn_s_setprio(1);                                                 \
  MM16(CH);                                                                      \
  __builtin_amdgcn_s_setprio(0);                                                 \
  BARR;

#define TILE(T, BUF)                                                             \
  { const int _kel = kbase + (T) * 64;                                           \
    LDA4(BUF, 0, 0); LDB4(BUF, 0);                                               \
    if ((T) + 1 < NT) STG(Ag, As[(BUF) ^ 1][1], _kel + 96);                      \
    PHASE_TAIL(0)                                                                \
    LDA4(BUF, 0, 1);                                                             \
    if ((T) + 1 < NT) STG(Bg, Bs[(BUF) ^ 1][1], _kel + 96);                      \
    PHASE_TAIL(1)                                                                \
    LDA4(BUF, 1, 0); LDB4(BUF, 1);                                               \
    if ((T) + 2 < NT) STG(Ag, As[BUF][0], _kel + 128);                           \
    PHASE_TAIL(0)                                                                \
    LDA4(BUF, 1, 1);                                                             \
    if ((T) + 2 < NT) STG(Bg, Bs[BUF][0], _kel + 128);                           \
    if ((T) + 2 < NT) { asm volatile("s_waitcnt vmcnt(4)" ::: "memory"); }       \
    else              { asm volatile("s_waitcnt vmcnt(0)" ::: "memory"); }       \
    PHASE_TAIL(1)                                                                \
  }

__device__ __forceinline__ void gemm_core(const short* __restrict__ Ag,
                                          const short* __restrict__ Bg,
                                          const size_t sK, const int kbase,
                                          const int NT, f4v (&acc)[8][4]) {
    __shared__ __align__(16) short As[2][2][8192];   // 64 KiB
    __shared__ __align__(16) short Bs[2][2][8192];   // 64 KiB
    const int tid = threadIdx.x;
    const int lane = tid & 63;
    const int wave = tid >> 6;
    const int wm = wave >> 2, wn = wave & 3;
    const int cq = lane & 15, quad = lane >> 4;
    // staging: lane l -> row (l>>2), phys chunk (l&3); source k pre-swizzled so
    // phys chunk c holds logical chunk c ^ ((row>>1)&3)
    const int gco = (((lane & 3) ^ ((lane >> 3) & 3)) << 3);
    const int rstage = wave * 32 + (lane >> 2);
    // read: logical chunk = quad -> phys = quad ^ ((row>>1)&3), row = ... + cq
    const int rc = ((quad ^ ((cq >> 1) & 3)) << 3);
    const int aoff = wm * 4096 + cq * 32 + rc;
    const int boff = wn * 2048 + cq * 32 + rc;

    s8v a[4], b[4];
    #pragma unroll
    for (int i = 0; i < 8; ++i)
        #pragma unroll
        for (int j = 0; j < 4; ++j) acc[i][j] = (f4v){0.f, 0.f, 0.f, 0.f};

    // prologue: tile0 (4 halves) + tile1 kh0 (2 halves); wait for tile0 only
    STG(Ag, As[0][0], kbase);
    STG(Bg, Bs[0][0], kbase);
    STG(Ag, As[0][1], kbase + 32);
    STG(Bg, Bs[0][1], kbase + 32);
    STG(Ag, As[1][0], kbase + 64);
    STG(Bg, Bs[1][0], kbase + 64);
    asm volatile("s_waitcnt vmcnt(4)" ::: "memory");
    BARR;

    #pragma unroll 1
    for (int t = 0; t < NT; t += 2) {
        TILE(t, 0)
        TILE(t + 1, 1)
    }
}

// ---------------- GEMM1: gu = hs @ W1[e] + b1[e]; act2 = rw*(up+1)*glu ----------------
// A: hsb [T][H] bf16. B: w1b [E][2D'][H] bf16 (deinterleaved B^T).
// Output: act2 [T][E*D] bf16. Grid (x=m=32, y=n=8, z=e=8), 512 thr.

__global__ __launch_bounds__(512, 2) void gemm1_kernel(
    const short* __restrict__ Ag0,      // hsb
    const short* __restrict__ Bg0,      // w1b
    const float* __restrict__ b1,       // [E][2D] original interleaved
    const float* __restrict__ rw,       // [T][E]
    __hip_bfloat16* __restrict__ act2)  // [T][E*D]
{
    const int e = blockIdx.z;
    const int mBase = blockIdx.x * 256;
    const int nBase = blockIdx.y * 256;
    const short* Ag = Ag0 + (size_t)mBase * H_DIM;
    const short* Bg = Bg0 + ((size_t)e * TWO_D + nBase) * H_DIM;

    f4v acc[8][4];
    gemm_core(Ag, Bg, H_DIM, 0, H_DIM / 64, acc);

    const int lane = threadIdx.x & 63, wave = threadIdx.x >> 6;
    const int wm = wave >> 2, wn = wave & 3;
    const int cq = lane & 15, quad = lane >> 4;

    // epilogue: even nf tile = gate, odd nf tile = up for the same D-cols.
    #pragma unroll
    for (int p = 0; p < 2; ++p) {
        const int j = (((nBase + wn * 64 + p * 32) >> 5) << 4) + cq;  // D-col
        const float gb = b1[(size_t)e * TWO_D + 2 * j];
        const float ub = b1[(size_t)e * TWO_D + 2 * j + 1];
        #pragma unroll
        for (int fm = 0; fm < 8; ++fm) {
            #pragma unroll
            for (int r = 0; r < 4; ++r) {
                const int row = mBase + wm * 128 + fm * 16 + quad * 4 + r;
                const float rwv = rw[(size_t)row * E_DIM + e];
                float gate = acc[fm][2 * p][r] + gb;
                float up   = acc[fm][2 * p + 1][r] + ub;
                gate = fminf(gate, LIMIT_C);
                up = fminf(fmaxf(up, -LIMIT_C), LIMIT_C);
                float glu = gate / (1.f + __expf(-ALPHA_C * gate));
                float av = (up + 1.f) * glu * rwv;
                act2[(size_t)row * K2 + (size_t)e * D_DIM + j] = __float2bfloat16(av);
            }
        }
    }
}

// ---------------- GEMM2 (split-K=2, no atomics): slice0 -> out fp32, slice1 ->
// bf16 partial. A: act2 [T][8192] bf16. B: w3b [H][8192] bf16 (B^T).
// Grid 256 = exactly 1 block/CU: n = id&3, m = (id>>2)&31, k = id>>7.

__global__ __launch_bounds__(512, 2) void gemm2_kernel(
    const short* __restrict__ Ag0,     // act2
    const short* __restrict__ Bg0,     // w3b
    float* __restrict__ out,           // [T][H] (k-slice 0)
    unsigned short* __restrict__ p0)   // [T][H] bf16 (k-slice 1)
{
    const int id = blockIdx.x;
    const int nBase = (id & 3) * 256;
    const int mBase = ((id >> 2) & 31) * 256;
    const int kIdx = id >> 7;
    const short* Ag = Ag0 + (size_t)mBase * K2;
    const short* Bg = Bg0 + (size_t)nBase * K2;

    f4v acc[8][4];
    gemm_core(Ag, Bg, K2, kIdx * 4096, 4096 / 64, acc);

    const int lane = threadIdx.x & 63, wave = threadIdx.x >> 6;
    const int wm = wave >> 2, wn = wave & 3;
    const int cq = lane & 15, quad = lane >> 4;

    #pragma unroll
    for (int fm = 0; fm < 8; ++fm) {
        #pragma unroll
        for (int r = 0; r < 4; ++r) {
            const int row = mBase + wm * 128 + fm * 16 + quad * 4 + r;
            #pragma unroll
            for (int nf = 0; nf < 4; ++nf) {
                const size_t o = (size_t)row * H_DIM + nBase + wn * 64 + nf * 16 + cq;
                if (kIdx == 0) out[o] = acc[fm][nf][r];
                else           p0[o]  = f2bf(acc[fm][nf][r]);
            }
        }
    }
}

// ---------------- launch ----------------

extern "C" void kernel_launch(void* const* d_in, const int* in_sizes, int n_in,
                              void* d_out, int out_size, void* d_ws, size_t ws_size,
                              hipStream_t stream) {
    const float* hs = (const float*)d_in[0];   // [T,H]
    const float* rw = (const float*)d_in[1];   // [T,E]
    const float* w1 = (const float*)d_in[2];   // [E,H,2D]
    const float* b1 = (const float*)d_in[3];   // [E,2D]
    const float* w3 = (const float*)d_in[4];   // [E,D,H]
    const float* b3 = (const float*)d_in[5];   // [E,H]
    float* out = (float*)d_out;

    char* ws = (char*)d_ws;
    unsigned short* hsb  = (unsigned short*)(ws);                          // 16 MB
    unsigned short* w1b  = (unsigned short*)(ws + ((size_t)16 << 20));     // 32 MB
    unsigned short* w3b  = (unsigned short*)(ws + ((size_t)48 << 20));     // 16 MB
    unsigned short* act2 = (unsigned short*)(ws + ((size_t)64 << 20));     // 128 MB
    // bf16 partial reuses hsb (dead after gemm1): 16 MB.
    unsigned short* p0 = (unsigned short*)(ws);

    // 1) hs -> bf16
    {
        size_t n = (size_t)T_DIM * H_DIM;  // 8388608
        f32_to_bf16_kernel<<<dim3(n / (256 * 4)), dim3(256), 0, stream>>>(hs, hsb, n);
    }
    // 2) W1 [E][H][2D] -> w1b [E][2D'][H] bf16 with gate/up 16-col deinterleave
    transpose_conv_kernel<<<dim3(TWO_D / 32, H_DIM / 32, E_DIM), dim3(256), 0, stream>>>(
        w1, w1b, TWO_D, (size_t)H_DIM * TWO_D, (size_t)TWO_D * H_DIM, (size_t)H_DIM, 1);
    // 3) W3 [E][D][H] -> w3b [H][E*D] bf16  (out idx = b*D + c*(E*D) + r)
    transpose_conv_kernel<<<dim3(H_DIM / 32, D_DIM / 32, E_DIM), dim3(256), 0, stream>>>(
        w3, w3b, H_DIM, (size_t)D_DIM * H_DIM, (size_t)D_DIM, (size_t)K2, 0);
    // 4) GEMM1 + GLU epilogue -> act2 (256^2 8-phase; x=m fastest for XCD B-sharing)
    gemm1_kernel<<<dim3(T_DIM / 256, TWO_D / 256, E_DIM), dim3(512), 0, stream>>>(
        (const short*)hsb, (const short*)w1b, b1, rw, (__hip_bfloat16*)act2);
    // 5) GEMM2 split-K=2 (exactly 256 blocks = 1/CU): slice0 -> out, slice1 -> p0
    gemm2_kernel<<<dim3(256), dim3(512), 0, stream>>>(
        (const short*)act2, (const short*)w3b, out, p0);
    // 6) out += p0 + sum_e rw*b3
    reduce_bias_kernel<<<dim3(T_DIM), dim3(H_DIM / 4), 0, stream>>>(
        p0, rw, b3, out);
}

// Round 2
// 625.268 us; speedup vs baseline: 1.0216x; 1.0216x over previous
//
#include <hip/hip_runtime.h>
#include <hip/hip_bf16.h>

// Problem constants: T=8192, H=1024, D=1024, E=8, 2D=2048, K2=E*D=8192
#define T_DIM 8192
#define H_DIM 1024
#define D_DIM 1024
#define E_DIM 8
#define TWO_D 2048
#define K2 8192

#define ALPHA_C 1.702f
#define LIMIT_C 7.0f

typedef __attribute__((ext_vector_type(8))) short s8v;   // 8 bf16 = 4 VGPRs
typedef __attribute__((ext_vector_type(4))) float f4v;   // MFMA accumulator

__device__ __forceinline__ void g2l16(const void* g, void* l) {
    // async global->LDS, 16B per lane; LDS dest = wave-uniform base + lane*16
    __builtin_amdgcn_global_load_lds((const __attribute__((address_space(1))) void*)g,
                                     (__attribute__((address_space(3))) void*)l, 16, 0, 0);
}

__device__ __forceinline__ unsigned short f2bf(float f) {
    __hip_bfloat16 h = __float2bfloat16(f);
    return __builtin_bit_cast(unsigned short, h);
}

__device__ __forceinline__ float bf2f(unsigned short u) {
    unsigned int x = ((unsigned int)u) << 16;
    return __builtin_bit_cast(float, x);
}

// ---------------- convert kernels ----------------

__global__ void f32_to_bf16_kernel(const float* __restrict__ in,
                                   unsigned short* __restrict__ out, size_t n) {
    size_t i = ((size_t)blockIdx.x * blockDim.x + threadIdx.x) * 4;
    if (i + 3 < n) {
        float4 v = *(const float4*)(in + i);
        ushort4 o;
        o.x = f2bf(v.x); o.y = f2bf(v.y); o.z = f2bf(v.z); o.w = f2bf(v.w);
        *(ushort4*)(out + i) = o;
    }
}

// out[b*obs + remap(c)*ors + r] = bf16(in[b*ibs + r*cols + c]); 32x32 tiles.
// remap==1: c -> (c&~31) + (c&1)*16 + ((c>>1)&15)   (gate/up 16-col deinterleave)
__global__ void transpose_conv_kernel(const float* __restrict__ in,
                                      unsigned short* __restrict__ out,
                                      int cols, size_t ibs, size_t obs, size_t ors,
                                      int remap) {
    __shared__ float t[32][33];
    const int b = blockIdx.z;
    const int c0 = blockIdx.x * 32, r0 = blockIdx.y * 32;
    const int tx = threadIdx.x & 31, ty = threadIdx.x >> 5;  // ty in 0..7
    const float* ip = in + (size_t)b * ibs;
    #pragma unroll
    for (int i = 0; i < 4; ++i)
        t[ty + i * 8][tx] = ip[(size_t)(r0 + ty + i * 8) * cols + c0 + tx];
    __syncthreads();
    unsigned short* op = out + (size_t)b * obs;
    #pragma unroll
    for (int i = 0; i < 4; ++i) {
        int c = c0 + ty + i * 8;
        int nc = remap ? ((c & ~31) + ((c & 1) << 4) + ((c >> 1) & 15)) : c;
        op[(size_t)nc * ors + r0 + tx] = f2bf(t[tx][ty + i * 8]);
    }
}

// out[t][h] += p0 (bf16 partial) + sum_e rw[t][e]*b3[e][h]
__global__ void reduce_bias_kernel(const unsigned short* __restrict__ p0,
                                   const float* __restrict__ rw,
                                   const float* __restrict__ b3,
                                   float* __restrict__ out) {
    const int t = blockIdx.x;
    const int h = threadIdx.x * 4;
    const size_t idx = (size_t)t * H_DIM + h;
    float r[E_DIM];
    #pragma unroll
    for (int e = 0; e < E_DIM; ++e) r[e] = rw[(size_t)t * E_DIM + e];
    float4 v = *(const float4*)(out + idx);
    ushort4 a = *(const ushort4*)(p0 + idx);
    v.x += bf2f(a.x);
    v.y += bf2f(a.y);
    v.z += bf2f(a.z);
    v.w += bf2f(a.w);
    #pragma unroll
    for (int e = 0; e < E_DIM; ++e) {
        float4 bb = *(const float4*)(b3 + (size_t)e * H_DIM + h);
        v.x += r[e] * bb.x; v.y += r[e] * bb.y; v.z += r[e] * bb.z; v.w += r[e] * bb.w;
    }
    *(float4*)(out + idx) = v;
}

// ---------------- 256x256 / BK=64 8-phase GEMM core (row-unit staging) ----------------
// Both operands K-major (A: [M][K], B: [N][K] bf16). 512 threads = 8 waves (2M x 4N),
// per-wave 128x64 output = acc[8][4] 16x16 fragments. LDS 128 KiB: As/Bs[2 dbuf]
// [256 rows x 64 elems] (128B rows -> full-cache-line staging, 8 rows per g2l16).
// 4 phases per K-tile (one C-half x one k-step = 16 MFMA each). During tile t (buf),
// 4 stage units for tile t+1 land in buf^1:
//   q0: A-ch0 (rows 0-63,128-191)   q1: B-lo (rows 0-127)
//   q2: B-hi (rows 128-255)         q3: A-ch1 (rows 64-127,192-255)
// Deadlines: A-ch0/B-lo/B-hi at t+1.q0 reads -> vmcnt(2) at q3-end (cover 3/2/1
// phases); A-ch1 at t+1.q1 reads -> vmcnt(2) at q0-end (cover 2 phases).
// Outstanding trajectory (2 loads/stage): 2 ->(q0 stage) 4 ->vmw(2)-> 2 -> 4 -> 6
// -> 8 ->vmw(2)-> 2.  Tail (t+1==NT): no stages, both waits vmcnt(0).
// Chunk swizzle: LDS[row][c_phys] = global chunk c_phys ^ (row&7); read at
// c_phys = c_log ^ (row&7) -> 8 consecutive lanes cover all 32 banks.

#define FEN asm volatile("" ::: "memory")
#define BARR { FEN; __builtin_amdgcn_s_barrier(); FEN; }
#define LGKM0 { asm volatile("s_waitcnt lgkmcnt(0)" ::: "memory"); \
                __builtin_amdgcn_sched_barrier(0); }
#define VMW2 asm volatile("s_waitcnt vmcnt(2)" ::: "memory")
#define VMW0 asm volatile("s_waitcnt vmcnt(0)" ::: "memory")

#define LDA4(BUF, KS, CH)                                                        \
  { const short* _p = &As[BUF][awm + (CH) * 4096 + ((KS) ? rc1 : rc0)];          \
    a[0] = *(const s8v*)(_p);        a[1] = *(const s8v*)(_p + 1024);            \
    a[2] = *(const s8v*)(_p + 2048); a[3] = *(const s8v*)(_p + 3072); }

#define LDB4(BUF, KS)                                                            \
  { const short* _p = &Bs[BUF][bwn + ((KS) ? rc1 : rc0)];                        \
    b[0] = *(const s8v*)(_p);        b[1] = *(const s8v*)(_p + 1024);            \
    b[2] = *(const s8v*)(_p + 2048); b[3] = *(const s8v*)(_p + 3072); }

#define MM16(CH)                                                                 \
  { _Pragma("unroll")                                                            \
    for (int mf = 0; mf < 4; ++mf) {                                             \
      _Pragma("unroll")                                                          \
      for (int nf = 0; nf < 4; ++nf)                                             \
        acc[(CH) * 4 + mf][nf] = __builtin_amdgcn_mfma_f32_16x16x32_bf16(        \
            a[mf], b[nf], acc[(CH) * 4 + mf][nf], 0, 0, 0);                      \
    } }

// A stage unit CH: LDS rows {CH*64..CH*64+63} U {128+CH*64..}; wave w covers 16 rows
#define STG_A(BUF, CH, KEL)                                                      \
  { const int _rb = (wave >> 2) * 128 + (wave & 3) * 16 + (CH) * 64;             \
    const short* _g = Ag + (size_t)(_rb + rloc) * sK + (KEL) + gco;              \
    short* _d = &As[BUF][_rb * 64];                                              \
    g2l16(_g, _d); g2l16(_g + 8 * sK, _d + 512); }

// B stage unit HALF: LDS rows HALF*128 .. +127; wave w covers 16 rows
#define STG_B(BUF, HALF, KEL)                                                    \
  { const int _rb = (HALF) * 128 + wave * 16;                                    \
    const short* _g = Bg + (size_t)(_rb + rloc) * sK + (KEL) + gco;              \
    short* _d = &Bs[BUF][_rb * 64];                                              \
    g2l16(_g, _d); g2l16(_g + 8 * sK, _d + 512); }

#define PRIO_MM(CH) { __builtin_amdgcn_s_setprio(1); MM16(CH);                   \
                      __builtin_amdgcn_s_setprio(0); }

#define TILE(T, BUF)                                                             \
  { const int _kel = kbase + ((T) + 1) * 64;                                     \
    const bool _pf = (T) + 1 < NT;                                               \
    LDA4(BUF, 0, 0); LDB4(BUF, 0);                                               \
    if (_pf) STG_A((BUF) ^ 1, 0, _kel);                                          \
    BARR; LGKM0; PRIO_MM(0);                                                     \
    if (_pf) { VMW2; } else { VMW0; }                                            \
    BARR;                                                                        \
    LDA4(BUF, 0, 1);                                                             \
    if (_pf) STG_B((BUF) ^ 1, 0, _kel);                                          \
    BARR; LGKM0; PRIO_MM(1); BARR;                                               \
    LDA4(BUF, 1, 0); LDB4(BUF, 1);                                               \
    if (_pf) STG_B((BUF) ^ 1, 1, _kel);                                          \
    BARR; LGKM0; PRIO_MM(0); BARR;                                               \
    LDA4(BUF, 1, 1);                                                             \
    if (_pf) STG_A((BUF) ^ 1, 1, _kel);                                          \
    BARR; LGKM0; PRIO_MM(1);                                                     \
    if (_pf) { VMW2; } else { VMW0; }                                            \
    BARR;                                                                        \
  }

__device__ __forceinline__ void gemm_core(const short* __restrict__ Ag,
                                          const short* __restrict__ Bg,
                                          const size_t sK, const int kbase,
                                          const int NT, f4v (&acc)[8][4]) {
    __shared__ __align__(16) short As[2][16384];   // 64 KiB
    __shared__ __align__(16) short Bs[2][16384];   // 64 KiB
    const int tid = threadIdx.x;
    const int lane = tid & 63;
    const int wave = tid >> 6;
    const int wm = wave >> 2, wn = wave & 3;
    const int cq = lane & 15, quad = lane >> 4;
    const int cq7 = cq & 7;
    const int rloc = lane >> 3;                       // 0..7: row within g2l16
    const int gco = (((lane & 7) ^ rloc)) * 8;        // pre-swizzled k-chunk (elems)
    const int awm = wm * 8192 + cq * 64;              // A read base (elems)
    const int bwn = wn * 4096 + cq * 64;              // B read base (elems)
    const int rc0 = (quad ^ cq7) * 8;                 // kstep0 phys chunk
    const int rc1 = ((quad + 4) ^ cq7) * 8;           // kstep1 phys chunk

    s8v a[4], b[4];
    #pragma unroll
    for (int i = 0; i < 8; ++i)
        #pragma unroll
        for (int j = 0; j < 4; ++j) acc[i][j] = (f4v){0.f, 0.f, 0.f, 0.f};

    // prologue: stage tile0 (A-ch0, B-lo, B-hi, A-ch1); last unit may lag (vmcnt(2))
    STG_A(0, 0, kbase);
    STG_B(0, 0, kbase);
    STG_B(0, 1, kbase);
    STG_A(0, 1, kbase);
    VMW2;
    BARR;

    #pragma unroll 1
    for (int t = 0; t < NT; t += 2) {
        TILE(t, 0)
        TILE(t + 1, 1)
    }
}

// ---------------- GEMM1: gu = hs @ W1[e] + b1[e]; act2 = rw*(up+1)*glu ----------------
// A: hsb [T][H] bf16. B: w1b [E][2D'][H] bf16 (deinterleaved B^T).
// Output: act2 [T][E*D] bf16. Grid (x=m=32, y=n=8, z=e=8), 512 thr.

__global__ __launch_bounds__(512, 2) void gemm1_kernel(
    const short* __restrict__ Ag0,      // hsb
    const short* __restrict__ Bg0,      // w1b
    const float* __restrict__ b1,       // [E][2D] original interleaved
    const float* __restrict__ rw,       // [T][E]
    __hip_bfloat16* __restrict__ act2)  // [T][E*D]
{
    const int e = blockIdx.z;
    const int mBase = blockIdx.x * 256;
    const int nBase = blockIdx.y * 256;
    const short* Ag = Ag0 + (size_t)mBase * H_DIM;
    const short* Bg = Bg0 + ((size_t)e * TWO_D + nBase) * H_DIM;

    f4v acc[8][4];
    gemm_core(Ag, Bg, H_DIM, 0, H_DIM / 64, acc);

    const int lane = threadIdx.x & 63, wave = threadIdx.x >> 6;
    const int wm = wave >> 2, wn = wave & 3;
    const int cq = lane & 15, quad = lane >> 4;

    // epilogue: even nf tile = gate, odd nf tile = up for the same D-cols.
    #pragma unroll
    for (int p = 0; p < 2; ++p) {
        const int j = (((nBase + wn * 64 + p * 32) >> 5) << 4) + cq;  // D-col
        const float gb = b1[(size_t)e * TWO_D + 2 * j];
        const float ub = b1[(size_t)e * TWO_D + 2 * j + 1];
        #pragma unroll
        for (int fm = 0; fm < 8; ++fm) {
            #pragma unroll
            for (int r = 0; r < 4; ++r) {
                const int row = mBase + wm * 128 + fm * 16 + quad * 4 + r;
                const float rwv = rw[(size_t)row * E_DIM + e];
                float gate = acc[fm][2 * p][r] + gb;
                float up   = acc[fm][2 * p + 1][r] + ub;
                gate = fminf(gate, LIMIT_C);
                up = fminf(fmaxf(up, -LIMIT_C), LIMIT_C);
                float glu = gate / (1.f + __expf(-ALPHA_C * gate));
                float av = (up + 1.f) * glu * rwv;
                act2[(size_t)row * K2 + (size_t)e * D_DIM + j] = __float2bfloat16(av);
            }
        }
    }
}

// ---------------- GEMM2 (split-K=2, no atomics): slice0 -> out fp32, slice1 ->
// bf16 partial. A: act2 [T][8192] bf16. B: w3b [H][8192] bf16 (B^T).
// Grid 256 = exactly 1 block/CU: n = id&3, m = (id>>2)&31, k = id>>7.

__global__ __launch_bounds__(512, 2) void gemm2_kernel(
    const short* __restrict__ Ag0,     // act2
    const short* __restrict__ Bg0,     // w3b
    float* __restrict__ out,           // [T][H] (k-slice 0)
    unsigned short* __restrict__ p0)   // [T][H] bf16 (k-slice 1)
{
    const int id = blockIdx.x;
    const int nBase = (id & 3) * 256;
    const int mBase = ((id >> 2) & 31) * 256;
    const int kIdx = id >> 7;
    const short* Ag = Ag0 + (size_t)mBase * K2;
    const short* Bg = Bg0 + (size_t)nBase * K2;

    f4v acc[8][4];
    gemm_core(Ag, Bg, K2, kIdx * 4096, 4096 / 64, acc);

    const int lane = threadIdx.x & 63, wave = threadIdx.x >> 6;
    const int wm = wave >> 2, wn = wave & 3;
    const int cq = lane & 15, quad = lane >> 4;

    #pragma unroll
    for (int fm = 0; fm < 8; ++fm) {
        #pragma unroll
        for (int r = 0; r < 4; ++r) {
            const int row = mBase + wm * 128 + fm * 16 + quad * 4 + r;
            #pragma unroll
            for (int nf = 0; nf < 4; ++nf) {
                const size_t o = (size_t)row * H_DIM + nBase + wn * 64 + nf * 16 + cq;
                if (kIdx == 0) out[o] = acc[fm][nf][r];
                else           p0[o]  = f2bf(acc[fm][nf][r]);
            }
        }
    }
}

// ---------------- launch ----------------

extern "C" void kernel_launch(void* const* d_in, const int* in_sizes, int n_in,
                              void* d_out, int out_size, void* d_ws, size_t ws_size,
                              hipStream_t stream) {
    const float* hs = (const float*)d_in[0];   // [T,H]
    const float* rw = (const float*)d_in[1];   // [T,E]
    const float* w1 = (const float*)d_in[2];   // [E,H,2D]
    const float* b1 = (const float*)d_in[3];   // [E,2D]
    const float* w3 = (const float*)d_in[4];   // [E,D,H]
    const float* b3 = (const float*)d_in[5];   // [E,H]
    float* out = (float*)d_out;

    char* ws = (char*)d_ws;
    unsigned short* hsb  = (unsigned short*)(ws);                          // 16 MB
    unsigned short* w1b  = (unsigned short*)(ws + ((size_t)16 << 20));     // 32 MB
    unsigned short* w3b  = (unsigned short*)(ws + ((size_t)48 << 20));     // 16 MB
    unsigned short* act2 = (unsigned short*)(ws + ((size_t)64 << 20));     // 128 MB
    // bf16 partial reuses hsb (dead after gemm1): 16 MB.
    unsigned short* p0 = (unsigned short*)(ws);

    // 1) hs -> bf16
    {
        size_t n = (size_t)T_DIM * H_DIM;  // 8388608
        f32_to_bf16_kernel<<<dim3(n / (256 * 4)), dim3(256), 0, stream>>>(hs, hsb, n);
    }
    // 2) W1 [E][H][2D] -> w1b [E][2D'][H] bf16 with gate/up 16-col deinterleave
    transpose_conv_kernel<<<dim3(TWO_D / 32, H_DIM / 32, E_DIM), dim3(256), 0, stream>>>(
        w1, w1b, TWO_D, (size_t)H_DIM * TWO_D, (size_t)TWO_D * H_DIM, (size_t)H_DIM, 1);
    // 3) W3 [E][D][H] -> w3b [H][E*D] bf16  (out idx = b*D + c*(E*D) + r)
    transpose_conv_kernel<<<dim3(H_DIM / 32, D_DIM / 32, E_DIM), dim3(256), 0, stream>>>(
        w3, w3b, H_DIM, (size_t)D_DIM * H_DIM, (size_t)D_DIM, (size_t)K2, 0);
    // 4) GEMM1 + GLU epilogue -> act2 (256^2 8-phase; x=m fastest for XCD B-sharing)
    gemm1_kernel<<<dim3(T_DIM / 256, TWO_D / 256, E_DIM), dim3(512), 0, stream>>>(
        (const short*)hsb, (const short*)w1b, b1, rw, (__hip_bfloat16*)act2);
    // 5) GEMM2 split-K=2 (exactly 256 blocks = 1/CU): slice0 -> out, slice1 -> p0
    gemm2_kernel<<<dim3(256), dim3(512), 0, stream>>>(
        (const short*)act2, (const short*)w3b, out, p0);
    // 6) out += p0 + sum_e rw*b3
    reduce_bias_kernel<<<dim3(T_DIM), dim3(H_DIM / 4), 0, stream>>>(
        p0, rw, b3, out);
}

// Round 3
// 607.241 us; speedup vs baseline: 1.0519x; 1.0297x over previous
//
#include <hip/hip_runtime.h>
#include <hip/hip_bf16.h>

// Problem constants: T=8192, H=1024, D=1024, E=8, 2D=2048, K2=E*D=8192
#define T_DIM 8192
#define H_DIM 1024
#define D_DIM 1024
#define E_DIM 8
#define TWO_D 2048
#define K2 8192

#define ALPHA_C 1.702f
#define LIMIT_C 7.0f

typedef __attribute__((ext_vector_type(8))) short s8v;   // 8 bf16 = 4 VGPRs
typedef __attribute__((ext_vector_type(4))) float f4v;   // MFMA accumulator

__device__ __forceinline__ void g2l16(const void* g, void* l) {
    // async global->LDS, 16B per lane; LDS dest = wave-uniform base + lane*16
    __builtin_amdgcn_global_load_lds((const __attribute__((address_space(1))) void*)g,
                                     (__attribute__((address_space(3))) void*)l, 16, 0, 0);
}

__device__ __forceinline__ unsigned short f2bf(float f) {
    __hip_bfloat16 h = __float2bfloat16(f);
    return __builtin_bit_cast(unsigned short, h);
}

// ---------------- convert kernels ----------------

__global__ void f32_to_bf16_kernel(const float* __restrict__ in,
                                   unsigned short* __restrict__ out, size_t n) {
    size_t i = ((size_t)blockIdx.x * blockDim.x + threadIdx.x) * 4;
    if (i + 3 < n) {
        float4 v = *(const float4*)(in + i);
        ushort4 o;
        o.x = f2bf(v.x); o.y = f2bf(v.y); o.z = f2bf(v.z); o.w = f2bf(v.w);
        *(ushort4*)(out + i) = o;
    }
}

// out[b*obs + remap(c)*ors + r] = bf16(in[b*ibs + r*cols + c]); 32x32 tiles.
// remap==1: c -> (c&~31) + (c&1)*16 + ((c>>1)&15)   (gate/up 16-col deinterleave)
__global__ void transpose_conv_kernel(const float* __restrict__ in,
                                      unsigned short* __restrict__ out,
                                      int cols, size_t ibs, size_t obs, size_t ors,
                                      int remap) {
    __shared__ float t[32][33];
    const int b = blockIdx.z;
    const int c0 = blockIdx.x * 32, r0 = blockIdx.y * 32;
    const int tx = threadIdx.x & 31, ty = threadIdx.x >> 5;  // ty in 0..7
    const float* ip = in + (size_t)b * ibs;
    #pragma unroll
    for (int i = 0; i < 4; ++i)
        t[ty + i * 8][tx] = ip[(size_t)(r0 + ty + i * 8) * cols + c0 + tx];
    __syncthreads();
    unsigned short* op = out + (size_t)b * obs;
    #pragma unroll
    for (int i = 0; i < 4; ++i) {
        int c = c0 + ty + i * 8;
        int nc = remap ? ((c & ~31) + ((c & 1) << 4) + ((c >> 1) & 15)) : c;
        op[(size_t)nc * ors + r0 + tx] = f2bf(t[tx][ty + i * 8]);
    }
}

// ---------------- GEMM1: gu = hs @ W1[e] + b1[e]; act2 = rw*(up+1)*glu ----------------
// BK=64, XOR-swizzled LDS chunks. A: hsb [T][H] bf16. B: w1b [E][2D'][H] bf16
// (deinterleaved B^T). Output: act2 [T][E*D] bf16.
// Grid: (x=m fastest, y=n, z=e) so 8 consecutive blocks (8 XCDs) share one B n-tile.

__global__ __launch_bounds__(256, 2) void gemm1_kernel(
    const short* __restrict__ Ag0,      // hsb
    const short* __restrict__ Bg0,      // w1b
    const float* __restrict__ b1,       // [E][2D] original interleaved
    const float* __restrict__ rw,       // [T][E]
    __hip_bfloat16* __restrict__ act2)  // [T][E*D]
{
    const int e = blockIdx.z;
    const int mBase = blockIdx.x * 128;
    const int nBase = blockIdx.y * 128;
    const int tid = threadIdx.x;
    const int lane = tid & 63;
    const int wave = tid >> 6;
    const int wm = wave >> 1, wn = wave & 1;
    const int cq = lane & 15, quad = lane >> 4;

    __shared__ __align__(16) short As[128 * 64];
    __shared__ __align__(16) short Bs[128 * 64];

    const short* Ag = Ag0 + (size_t)mBase * H_DIM;
    const short* Bg = Bg0 + ((size_t)e * TWO_D + nBase) * H_DIM;

    f4v acc[4][4];
    #pragma unroll
    for (int mt = 0; mt < 4; ++mt)
        #pragma unroll
        for (int nt = 0; nt < 4; ++nt)
            acc[mt][nt] = (f4v){0.f, 0.f, 0.f, 0.f};

    const int srow8 = lane >> 3;                 // 0..7
    const int gco = ((lane & 7) ^ srow8) * 8;    // swizzled global k-offset (elements)
    const int cq7 = cq & 7;

    for (int k0 = 0; k0 < H_DIM; k0 += 64) {
        #pragma unroll
        for (int i = 0; i < 4; ++i) {
            const int r = wave * 32 + i * 8 + srow8;
            g2l16(Ag + (size_t)r * H_DIM + k0 + gco, As + (wave * 32 + i * 8) * 64);
            g2l16(Bg + (size_t)r * H_DIM + k0 + gco, Bs + (wave * 32 + i * 8) * 64);
        }
        __syncthreads();
        #pragma unroll
        for (int h = 0; h < 2; ++h) {
            s8v af[4], bf[4];
            const int pc = (((h << 2) + quad) ^ cq7) * 8;  // phys chunk offset (elements)
            #pragma unroll
            for (int i = 0; i < 4; ++i) {
                af[i] = *(const s8v*)(As + (wm * 64 + i * 16 + cq) * 64 + pc);
                bf[i] = *(const s8v*)(Bs + (wn * 64 + i * 16 + cq) * 64 + pc);
            }
            #pragma unroll
            for (int mt = 0; mt < 4; ++mt)
                #pragma unroll
                for (int nt = 0; nt < 4; ++nt)
                    acc[mt][nt] = __builtin_amdgcn_mfma_f32_16x16x32_bf16(
                        af[mt], bf[nt], acc[mt][nt], 0, 0, 0);
        }
        __syncthreads();
    }

    // epilogue: even nt tile = gate, odd nt tile = up for the same D-cols.
    float rwv[4][4];
    #pragma unroll
    for (int mt = 0; mt < 4; ++mt)
        #pragma unroll
        for (int r = 0; r < 4; ++r)
            rwv[mt][r] = rw[(size_t)(mBase + wm * 64 + mt * 16 + quad * 4 + r) * E_DIM + e];

    #pragma unroll
    for (int p = 0; p < 2; ++p) {
        const int j = (((nBase + wn * 64 + p * 32) >> 5) << 4) + cq;   // D-col in [0,1024)
        const float gb = b1[(size_t)e * TWO_D + 2 * j];
        const float ub = b1[(size_t)e * TWO_D + 2 * j + 1];
        #pragma unroll
        for (int mt = 0; mt < 4; ++mt) {
            #pragma unroll
            for (int r = 0; r < 4; ++r) {
                float gate = acc[mt][2 * p][r] + gb;
                float up   = acc[mt][2 * p + 1][r] + ub;
                gate = fminf(gate, LIMIT_C);
                up = fminf(fmaxf(up, -LIMIT_C), LIMIT_C);
                float glu = gate / (1.f + __expf(-ALPHA_C * gate));
                float a = (up + 1.f) * glu * rwv[mt][r];
                const int row = mBase + wm * 64 + mt * 16 + quad * 4 + r;
                act2[(size_t)row * K2 + (size_t)e * D_DIM + j] = __float2bfloat16(a);
            }
        }
    }
}

// ---------------- GEMM2 single-pass: out = act2 @ w3b^T + sum_e rw*b3 ----------------
// A: act2 [T][8192] bf16. B: w3b [H][8192] bf16 (B^T). K=8192 in one block (128
// BK=64 steps). Grid 512 = 2 blocks/CU. id: n = id&7 (XCD-pinned B column, 2 MB
// fits per-XCD L2), m = id>>3 (A-tile shared across XCDs via L3). Epilogue fuses
// the routing-weighted down_proj bias: out += sum_e rw[row][e]*b3[e][col].

__global__ __launch_bounds__(256, 2) void gemm2_kernel(
    const short* __restrict__ Ag0,     // act2
    const short* __restrict__ Bg0,     // w3b
    const float* __restrict__ rw,      // [T][E]
    const float* __restrict__ b3,      // [E][H]
    float* __restrict__ out)           // [T][H]
{
    const int id = blockIdx.x;
    const int nBase = (id & 7) * 128;
    const int mBase = (id >> 3) * 128;
    const int tid = threadIdx.x;
    const int lane = tid & 63;
    const int wave = tid >> 6;
    const int wm = wave >> 1, wn = wave & 1;
    const int cq = lane & 15, quad = lane >> 4;

    __shared__ __align__(16) short As[128 * 64];
    __shared__ __align__(16) short Bs[128 * 64];

    const short* Ag = Ag0 + (size_t)mBase * K2;
    const short* Bg = Bg0 + (size_t)nBase * K2;

    f4v acc[4][4];
    #pragma unroll
    for (int mt = 0; mt < 4; ++mt)
        #pragma unroll
        for (int nt = 0; nt < 4; ++nt)
            acc[mt][nt] = (f4v){0.f, 0.f, 0.f, 0.f};

    const int srow8 = lane >> 3;
    const int gco = ((lane & 7) ^ srow8) * 8;
    const int cq7 = cq & 7;

    for (int k0 = 0; k0 < K2; k0 += 64) {
        #pragma unroll
        for (int i = 0; i < 4; ++i) {
            const int r = wave * 32 + i * 8 + srow8;
            g2l16(Ag + (size_t)r * K2 + k0 + gco, As + (wave * 32 + i * 8) * 64);
            g2l16(Bg + (size_t)r * K2 + k0 + gco, Bs + (wave * 32 + i * 8) * 64);
        }
        __syncthreads();
        #pragma unroll
        for (int h = 0; h < 2; ++h) {
            s8v af[4], bf[4];
            const int pc = (((h << 2) + quad) ^ cq7) * 8;
            #pragma unroll
            for (int i = 0; i < 4; ++i) {
                af[i] = *(const s8v*)(As + (wm * 64 + i * 16 + cq) * 64 + pc);
                bf[i] = *(const s8v*)(Bs + (wn * 64 + i * 16 + cq) * 64 + pc);
            }
            #pragma unroll
            for (int mt = 0; mt < 4; ++mt)
                #pragma unroll
                for (int nt = 0; nt < 4; ++nt)
                    acc[mt][nt] = __builtin_amdgcn_mfma_f32_16x16x32_bf16(
                        af[mt], bf[nt], acc[mt][nt], 0, 0, 0);
        }
        __syncthreads();
    }

    // epilogue: out = acc + sum_e rw[row][e] * b3[e][col]
    // b3[e][col] is loop-invariant over (mt,r) -> compiler hoists to 32 regs.
    #pragma unroll
    for (int mt = 0; mt < 4; ++mt) {
        #pragma unroll
        for (int r = 0; r < 4; ++r) {
            const int row = mBase + wm * 64 + mt * 16 + quad * 4 + r;
            const float4 rwa = *(const float4*)(rw + (size_t)row * E_DIM);
            const float4 rwb = *(const float4*)(rw + (size_t)row * E_DIM + 4);
            #pragma unroll
            for (int nt = 0; nt < 4; ++nt) {
                const int col = nBase + wn * 64 + nt * 16 + cq;
                float bias = rwa.x * b3[0 * H_DIM + col] + rwa.y * b3[1 * H_DIM + col]
                           + rwa.z * b3[2 * H_DIM + col] + rwa.w * b3[3 * H_DIM + col]
                           + rwb.x * b3[4 * H_DIM + col] + rwb.y * b3[5 * H_DIM + col]
                           + rwb.z * b3[6 * H_DIM + col] + rwb.w * b3[7 * H_DIM + col];
                out[(size_t)row * H_DIM + col] = acc[mt][nt][r] + bias;
            }
        }
    }
}

// ---------------- launch ----------------

extern "C" void kernel_launch(void* const* d_in, const int* in_sizes, int n_in,
                              void* d_out, int out_size, void* d_ws, size_t ws_size,
                              hipStream_t stream) {
    const float* hs = (const float*)d_in[0];   // [T,H]
    const float* rw = (const float*)d_in[1];   // [T,E]
    const float* w1 = (const float*)d_in[2];   // [E,H,2D]
    const float* b1 = (const float*)d_in[3];   // [E,2D]
    const float* w3 = (const float*)d_in[4];   // [E,D,H]
    const float* b3 = (const float*)d_in[5];   // [E,H]
    float* out = (float*)d_out;

    char* ws = (char*)d_ws;
    unsigned short* hsb  = (unsigned short*)(ws);                          // 16 MB
    unsigned short* w1b  = (unsigned short*)(ws + ((size_t)16 << 20));     // 32 MB
    unsigned short* w3b  = (unsigned short*)(ws + ((size_t)48 << 20));     // 16 MB
    unsigned short* act2 = (unsigned short*)(ws + ((size_t)64 << 20));     // 128 MB

    // 1) hs -> bf16
    {
        size_t n = (size_t)T_DIM * H_DIM;  // 8388608
        f32_to_bf16_kernel<<<dim3(n / (256 * 4)), dim3(256), 0, stream>>>(hs, hsb, n);
    }
    // 2) W1 [E][H][2D] -> w1b [E][2D'][H] bf16 with gate/up 16-col deinterleave
    transpose_conv_kernel<<<dim3(TWO_D / 32, H_DIM / 32, E_DIM), dim3(256), 0, stream>>>(
        w1, w1b, TWO_D, (size_t)H_DIM * TWO_D, (size_t)TWO_D * H_DIM, (size_t)H_DIM, 1);
    // 3) W3 [E][D][H] -> w3b [H][E*D] bf16  (out idx = b*D + c*(E*D) + r)
    transpose_conv_kernel<<<dim3(H_DIM / 32, D_DIM / 32, E_DIM), dim3(256), 0, stream>>>(
        w3, w3b, H_DIM, (size_t)D_DIM * H_DIM, (size_t)D_DIM, (size_t)K2, 0);
    // 4) GEMM1 + GLU epilogue -> act2  (x=m fastest for XCD B-sharing)
    gemm1_kernel<<<dim3(T_DIM / 128, TWO_D / 128, E_DIM), dim3(256), 0, stream>>>(
        (const short*)hsb, (const short*)w1b, b1, rw, (__hip_bfloat16*)act2);
    // 5) GEMM2 single-pass (512 blocks = 2/CU), bias fused -> out
    gemm2_kernel<<<dim3(512), dim3(256), 0, stream>>>(
        (const short*)act2, (const short*)w3b, rw, b3, out);
}

// Round 4
// 606.822 us; speedup vs baseline: 1.0526x; 1.0007x over previous
//
#include <hip/hip_runtime.h>
#include <hip/hip_bf16.h>

// Problem constants: T=8192, H=1024, D=1024, E=8, 2D=2048, K2=E*D=8192
#define T_DIM 8192
#define H_DIM 1024
#define D_DIM 1024
#define E_DIM 8
#define TWO_D 2048
#define K2 8192

#define ALPHA_C 1.702f
#define LIMIT_C 7.0f

typedef __attribute__((ext_vector_type(8))) short s8v;   // 8 bf16 = 4 VGPRs
typedef __attribute__((ext_vector_type(4))) float f4v;   // MFMA accumulator

__device__ __forceinline__ void g2l16(const void* g, void* l) {
    // async global->LDS, 16B per lane; LDS dest = wave-uniform base + lane*16
    __builtin_amdgcn_global_load_lds((const __attribute__((address_space(1))) void*)g,
                                     (__attribute__((address_space(3))) void*)l, 16, 0, 0);
}

__device__ __forceinline__ unsigned short f2bf(float f) {
    __hip_bfloat16 h = __float2bfloat16(f);
    return __builtin_bit_cast(unsigned short, h);
}

// ---------------- convert kernels ----------------

__global__ void f32_to_bf16_kernel(const float* __restrict__ in,
                                   unsigned short* __restrict__ out, size_t n) {
    size_t i = ((size_t)blockIdx.x * blockDim.x + threadIdx.x) * 4;
    if (i + 3 < n) {
        float4 v = *(const float4*)(in + i);
        ushort4 o;
        o.x = f2bf(v.x); o.y = f2bf(v.y); o.z = f2bf(v.z); o.w = f2bf(v.w);
        *(ushort4*)(out + i) = o;
    }
}

// out[b*obs + remap(c)*ors + r] = bf16(in[b*ibs + r*cols + c]); 32x32 tiles.
// remap==1: c -> (c&~31) + (c&1)*16 + ((c>>1)&15)   (gate/up 16-col deinterleave)
__global__ void transpose_conv_kernel(const float* __restrict__ in,
                                      unsigned short* __restrict__ out,
                                      int cols, size_t ibs, size_t obs, size_t ors,
                                      int remap) {
    __shared__ float t[32][33];
    const int b = blockIdx.z;
    const int c0 = blockIdx.x * 32, r0 = blockIdx.y * 32;
    const int tx = threadIdx.x & 31, ty = threadIdx.x >> 5;  // ty in 0..7
    const float* ip = in + (size_t)b * ibs;
    #pragma unroll
    for (int i = 0; i < 4; ++i)
        t[ty + i * 8][tx] = ip[(size_t)(r0 + ty + i * 8) * cols + c0 + tx];
    __syncthreads();
    unsigned short* op = out + (size_t)b * obs;
    #pragma unroll
    for (int i = 0; i < 4; ++i) {
        int c = c0 + ty + i * 8;
        int nc = remap ? ((c & ~31) + ((c & 1) << 4) + ((c >> 1) & 15)) : c;
        op[(size_t)nc * ors + r0 + tx] = f2bf(t[tx][ty + i * 8]);
    }
}

// ---------------- GEMM1: gu = hs @ W1[e] + b1[e]; act2 = rw*(up+1)*glu ----------------
// BK=64, XOR-swizzled LDS chunks. A: hsb [T][H] bf16. B: w1b [E][2D'][H] bf16
// (deinterleaved B^T). Output: act2 [T][E*D] bf16.
// Grid: (x=m fastest, y=n, z=e) so 8 consecutive blocks (8 XCDs) share one B n-tile.

__global__ __launch_bounds__(256, 2) void gemm1_kernel(
    const short* __restrict__ Ag0,      // hsb
    const short* __restrict__ Bg0,      // w1b
    const float* __restrict__ b1,       // [E][2D] original interleaved
    const float* __restrict__ rw,       // [T][E]
    __hip_bfloat16* __restrict__ act2)  // [T][E*D]
{
    const int e = blockIdx.z;
    const int mBase = blockIdx.x * 128;
    const int nBase = blockIdx.y * 128;
    const int tid = threadIdx.x;
    const int lane = tid & 63;
    const int wave = tid >> 6;
    const int wm = wave >> 1, wn = wave & 1;
    const int cq = lane & 15, quad = lane >> 4;

    __shared__ __align__(16) short As[128 * 64];
    __shared__ __align__(16) short Bs[128 * 64];

    const short* Ag = Ag0 + (size_t)mBase * H_DIM;
    const short* Bg = Bg0 + ((size_t)e * TWO_D + nBase) * H_DIM;

    f4v acc[4][4];
    #pragma unroll
    for (int mt = 0; mt < 4; ++mt)
        #pragma unroll
        for (int nt = 0; nt < 4; ++nt)
            acc[mt][nt] = (f4v){0.f, 0.f, 0.f, 0.f};

    const int srow8 = lane >> 3;                 // 0..7
    const int gco = ((lane & 7) ^ srow8) * 8;    // swizzled global k-offset (elements)
    const int cq7 = cq & 7;

    for (int k0 = 0; k0 < H_DIM; k0 += 64) {
        #pragma unroll
        for (int i = 0; i < 4; ++i) {
            const int r = wave * 32 + i * 8 + srow8;
            g2l16(Ag + (size_t)r * H_DIM + k0 + gco, As + (wave * 32 + i * 8) * 64);
            g2l16(Bg + (size_t)r * H_DIM + k0 + gco, Bs + (wave * 32 + i * 8) * 64);
        }
        __syncthreads();
        #pragma unroll
        for (int h = 0; h < 2; ++h) {
            s8v af[4], bf[4];
            const int pc = (((h << 2) + quad) ^ cq7) * 8;  // phys chunk offset (elements)
            #pragma unroll
            for (int i = 0; i < 4; ++i) {
                af[i] = *(const s8v*)(As + (wm * 64 + i * 16 + cq) * 64 + pc);
                bf[i] = *(const s8v*)(Bs + (wn * 64 + i * 16 + cq) * 64 + pc);
            }
            #pragma unroll
            for (int mt = 0; mt < 4; ++mt)
                #pragma unroll
                for (int nt = 0; nt < 4; ++nt)
                    acc[mt][nt] = __builtin_amdgcn_mfma_f32_16x16x32_bf16(
                        af[mt], bf[nt], acc[mt][nt], 0, 0, 0);
        }
        __syncthreads();
    }

    // epilogue: even nt tile = gate, odd nt tile = up for the same D-cols.
    float rwv[4][4];
    #pragma unroll
    for (int mt = 0; mt < 4; ++mt)
        #pragma unroll
        for (int r = 0; r < 4; ++r)
            rwv[mt][r] = rw[(size_t)(mBase + wm * 64 + mt * 16 + quad * 4 + r) * E_DIM + e];

    #pragma unroll
    for (int p = 0; p < 2; ++p) {
        const int j = (((nBase + wn * 64 + p * 32) >> 5) << 4) + cq;   // D-col in [0,1024)
        const float gb = b1[(size_t)e * TWO_D + 2 * j];
        const float ub = b1[(size_t)e * TWO_D + 2 * j + 1];
        #pragma unroll
        for (int mt = 0; mt < 4; ++mt) {
            #pragma unroll
            for (int r = 0; r < 4; ++r) {
                float gate = acc[mt][2 * p][r] + gb;
                float up   = acc[mt][2 * p + 1][r] + ub;
                gate = fminf(gate, LIMIT_C);
                up = fminf(fmaxf(up, -LIMIT_C), LIMIT_C);
                float glu = gate / (1.f + __expf(-ALPHA_C * gate));
                float a = (up + 1.f) * glu * rwv[mt][r];
                const int row = mBase + wm * 64 + mt * 16 + quad * 4 + r;
                act2[(size_t)row * K2 + (size_t)e * D_DIM + j] = __float2bfloat16(a);
            }
        }
    }
}

// ---------------- GEMM2 single-pass, 2-phase pipelined ----------------
// out = act2 @ w3b^T + sum_e rw*b3. A: act2 [T][8192] bf16 (L3-resident, long
// latency). B: w3b [H][8192] bf16. K=8192, 128 BK=64 steps. Grid 512 = 2/CU.
// id: n = id&7 (XCD-pinned B column), m = id>>3 (A-tile shared via L3).
// T3 minimum-2-phase: double-buffered LDS; stage tile t+1 BEFORE computing tile t,
// then one vmcnt(0) + raw s_barrier per iteration AFTER the MFMA cluster — the
// ds_read+MFMA phase (~700 cy) covers the L3 fetch latency instead of fronting it.
// Ledger: a wave past the barrier has retired lgkmcnt(0) (its reads of the buffer
// to be overwritten are done) and vmcnt(0) (staged tile landed). Tail: last iter
// stages nothing; vmcnt(0) is trivially satisfied.

#define FEN asm volatile("" ::: "memory")
#define BARR { FEN; __builtin_amdgcn_s_barrier(); FEN; }
#define VMW0 asm volatile("s_waitcnt vmcnt(0)" ::: "memory")

__global__ __launch_bounds__(256, 2) void gemm2_kernel(
    const short* __restrict__ Ag0,     // act2
    const short* __restrict__ Bg0,     // w3b
    const float* __restrict__ rw,      // [T][E]
    const float* __restrict__ b3,      // [E][H]
    float* __restrict__ out)           // [T][H]
{
    const int id = blockIdx.x;
    const int nBase = (id & 7) * 128;
    const int mBase = (id >> 3) * 128;
    const int tid = threadIdx.x;
    const int lane = tid & 63;
    const int wave = tid >> 6;
    const int wm = wave >> 1, wn = wave & 1;
    const int cq = lane & 15, quad = lane >> 4;

    __shared__ __align__(16) short As[2][128 * 64];   // 32 KiB
    __shared__ __align__(16) short Bs[2][128 * 64];   // 32 KiB

    const short* Ag = Ag0 + (size_t)mBase * K2;
    const short* Bg = Bg0 + (size_t)nBase * K2;

    f4v acc[4][4];
    #pragma unroll
    for (int mt = 0; mt < 4; ++mt)
        #pragma unroll
        for (int nt = 0; nt < 4; ++nt)
            acc[mt][nt] = (f4v){0.f, 0.f, 0.f, 0.f};

    const int srow8 = lane >> 3;
    const int gco = ((lane & 7) ^ srow8) * 8;
    const int cq7 = cq & 7;

    // prologue: stage tile 0, wait, barrier
    #pragma unroll
    for (int i = 0; i < 4; ++i) {
        const int r = wave * 32 + i * 8 + srow8;
        g2l16(Ag + (size_t)r * K2 + 0 + gco, &As[0][(wave * 32 + i * 8) * 64]);
        g2l16(Bg + (size_t)r * K2 + 0 + gco, &Bs[0][(wave * 32 + i * 8) * 64]);
    }
    VMW0;
    BARR;

    int cur = 0;
    #pragma unroll 1
    for (int k0 = 0; k0 < K2; k0 += 64) {
        // issue next tile's stages first (latency hides under this tile's compute)
        if (k0 + 64 < K2) {
            #pragma unroll
            for (int i = 0; i < 4; ++i) {
                const int r = wave * 32 + i * 8 + srow8;
                g2l16(Ag + (size_t)r * K2 + k0 + 64 + gco,
                      &As[cur ^ 1][(wave * 32 + i * 8) * 64]);
                g2l16(Bg + (size_t)r * K2 + k0 + 64 + gco,
                      &Bs[cur ^ 1][(wave * 32 + i * 8) * 64]);
            }
        }
        FEN;  // keep stages issued before the compute phase
        const short* Ab = As[cur];
        const short* Bb = Bs[cur];
        __builtin_amdgcn_s_setprio(1);
        #pragma unroll
        for (int h = 0; h < 2; ++h) {
            s8v af[4], bf[4];
            const int pc = (((h << 2) + quad) ^ cq7) * 8;
            #pragma unroll
            for (int i = 0; i < 4; ++i) {
                af[i] = *(const s8v*)(Ab + (wm * 64 + i * 16 + cq) * 64 + pc);
                bf[i] = *(const s8v*)(Bb + (wn * 64 + i * 16 + cq) * 64 + pc);
            }
            #pragma unroll
            for (int mt = 0; mt < 4; ++mt)
                #pragma unroll
                for (int nt = 0; nt < 4; ++nt)
                    acc[mt][nt] = __builtin_amdgcn_mfma_f32_16x16x32_bf16(
                        af[mt], bf[nt], acc[mt][nt], 0, 0, 0);
        }
        __builtin_amdgcn_s_setprio(0);
        VMW0;   // staged tile t+1 fully landed
        BARR;   // all waves done reading buf[cur] and staging
        cur ^= 1;
    }

    // epilogue: out = acc + sum_e rw[row][e] * b3[e][col]
    #pragma unroll
    for (int mt = 0; mt < 4; ++mt) {
        #pragma unroll
        for (int r = 0; r < 4; ++r) {
            const int row = mBase + wm * 64 + mt * 16 + quad * 4 + r;
            const float4 rwa = *(const float4*)(rw + (size_t)row * E_DIM);
            const float4 rwb = *(const float4*)(rw + (size_t)row * E_DIM + 4);
            #pragma unroll
            for (int nt = 0; nt < 4; ++nt) {
                const int col = nBase + wn * 64 + nt * 16 + cq;
                float bias = rwa.x * b3[0 * H_DIM + col] + rwa.y * b3[1 * H_DIM + col]
                           + rwa.z * b3[2 * H_DIM + col] + rwa.w * b3[3 * H_DIM + col]
                           + rwb.x * b3[4 * H_DIM + col] + rwb.y * b3[5 * H_DIM + col]
                           + rwb.z * b3[6 * H_DIM + col] + rwb.w * b3[7 * H_DIM + col];
                out[(size_t)row * H_DIM + col] = acc[mt][nt][r] + bias;
            }
        }
    }
}

// ---------------- launch ----------------

extern "C" void kernel_launch(void* const* d_in, const int* in_sizes, int n_in,
                              void* d_out, int out_size, void* d_ws, size_t ws_size,
                              hipStream_t stream) {
    const float* hs = (const float*)d_in[0];   // [T,H]
    const float* rw = (const float*)d_in[1];   // [T,E]
    const float* w1 = (const float*)d_in[2];   // [E,H,2D]
    const float* b1 = (const float*)d_in[3];   // [E,2D]
    const float* w3 = (const float*)d_in[4];   // [E,D,H]
    const float* b3 = (const float*)d_in[5];   // [E,H]
    float* out = (float*)d_out;

    char* ws = (char*)d_ws;
    unsigned short* hsb  = (unsigned short*)(ws);                          // 16 MB
    unsigned short* w1b  = (unsigned short*)(ws + ((size_t)16 << 20));     // 32 MB
    unsigned short* w3b  = (unsigned short*)(ws + ((size_t)48 << 20));     // 16 MB
    unsigned short* act2 = (unsigned short*)(ws + ((size_t)64 << 20));     // 128 MB

    // 1) hs -> bf16
    {
        size_t n = (size_t)T_DIM * H_DIM;  // 8388608
        f32_to_bf16_kernel<<<dim3(n / (256 * 4)), dim3(256), 0, stream>>>(hs, hsb, n);
    }
    // 2) W1 [E][H][2D] -> w1b [E][2D'][H] bf16 with gate/up 16-col deinterleave
    transpose_conv_kernel<<<dim3(TWO_D / 32, H_DIM / 32, E_DIM), dim3(256), 0, stream>>>(
        w1, w1b, TWO_D, (size_t)H_DIM * TWO_D, (size_t)TWO_D * H_DIM, (size_t)H_DIM, 1);
    // 3) W3 [E][D][H] -> w3b [H][E*D] bf16  (out idx = b*D + c*(E*D) + r)
    transpose_conv_kernel<<<dim3(H_DIM / 32, D_DIM / 32, E_DIM), dim3(256), 0, stream>>>(
        w3, w3b, H_DIM, (size_t)D_DIM * H_DIM, (size_t)D_DIM, (size_t)K2, 0);
    // 4) GEMM1 + GLU epilogue -> act2  (x=m fastest for XCD B-sharing)
    gemm1_kernel<<<dim3(T_DIM / 128, TWO_D / 128, E_DIM), dim3(256), 0, stream>>>(
        (const short*)hsb, (const short*)w1b, b1, rw, (__hip_bfloat16*)act2);
    // 5) GEMM2 single-pass 2-phase (512 blocks = 2/CU), bias fused -> out
    gemm2_kernel<<<dim3(512), dim3(256), 0, stream>>>(
        (const short*)act2, (const short*)w3b, rw, b3, out);
}

// Round 5
// 577.407 us; speedup vs baseline: 1.1062x; 1.0509x over previous
//
#include <hip/hip_runtime.h>
#include <hip/hip_bf16.h>

// Problem constants: T=8192, H=1024, D=1024, E=8, 2D=2048, K2=E*D=8192
#define T_DIM 8192
#define H_DIM 1024
#define D_DIM 1024
#define E_DIM 8
#define TWO_D 2048
#define K2 8192

#define ALPHA_C 1.702f
#define LIMIT_C 7.0f

typedef __attribute__((ext_vector_type(8))) short s8v;   // 8 bf16 = 4 VGPRs
typedef __attribute__((ext_vector_type(4))) float f4v;   // MFMA accumulator

__device__ __forceinline__ void g2l16(const void* g, void* l) {
    // async global->LDS, 16B per lane; LDS dest = wave-uniform base + lane*16
    __builtin_amdgcn_global_load_lds((const __attribute__((address_space(1))) void*)g,
                                     (__attribute__((address_space(3))) void*)l, 16, 0, 0);
}

__device__ __forceinline__ unsigned short f2bf(float f) {
    __hip_bfloat16 h = __float2bfloat16(f);
    return __builtin_bit_cast(unsigned short, h);
}

// ---------------- convert kernels ----------------

__global__ void f32_to_bf16_kernel(const float* __restrict__ in,
                                   unsigned short* __restrict__ out, size_t n) {
    size_t i = ((size_t)blockIdx.x * blockDim.x + threadIdx.x) * 4;
    if (i + 3 < n) {
        float4 v = *(const float4*)(in + i);
        ushort4 o;
        o.x = f2bf(v.x); o.y = f2bf(v.y); o.z = f2bf(v.z); o.w = f2bf(v.w);
        *(ushort4*)(out + i) = o;
    }
}

// out[b*obs + remap(c)*ors + r] = bf16(in[b*ibs + r*cols + c]); 32x32 tiles.
// remap==1: c -> (c&~31) + (c&1)*16 + ((c>>1)&15)   (gate/up 16-col deinterleave)
__global__ void transpose_conv_kernel(const float* __restrict__ in,
                                      unsigned short* __restrict__ out,
                                      int cols, size_t ibs, size_t obs, size_t ors,
                                      int remap) {
    __shared__ float t[32][33];
    const int b = blockIdx.z;
    const int c0 = blockIdx.x * 32, r0 = blockIdx.y * 32;
    const int tx = threadIdx.x & 31, ty = threadIdx.x >> 5;  // ty in 0..7
    const float* ip = in + (size_t)b * ibs;
    #pragma unroll
    for (int i = 0; i < 4; ++i)
        t[ty + i * 8][tx] = ip[(size_t)(r0 + ty + i * 8) * cols + c0 + tx];
    __syncthreads();
    unsigned short* op = out + (size_t)b * obs;
    #pragma unroll
    for (int i = 0; i < 4; ++i) {
        int c = c0 + ty + i * 8;
        int nc = remap ? ((c & ~31) + ((c & 1) << 4) + ((c >> 1) & 15)) : c;
        op[(size_t)nc * ors + r0 + tx] = f2bf(t[tx][ty + i * 8]);
    }
}

// ---------------- GEMM1: gu = hs @ W1[e] + b1[e]; act2 = rw*(up+1)*glu ----------------
// BK=64, XOR-swizzled LDS chunks. A: hsb [T][H] bf16. B: w1b [E][2D'][H] bf16
// (deinterleaved B^T). Output: act2 [T][E*D] bf16.
// Grid: (x=m fastest, y=n, z=e) so 8 consecutive blocks (8 XCDs) share one B n-tile.

__global__ __launch_bounds__(256, 2) void gemm1_kernel(
    const short* __restrict__ Ag0,      // hsb
    const short* __restrict__ Bg0,      // w1b
    const float* __restrict__ b1,       // [E][2D] original interleaved
    const float* __restrict__ rw,       // [T][E]
    __hip_bfloat16* __restrict__ act2)  // [T][E*D]
{
    const int e = blockIdx.z;
    const int mBase = blockIdx.x * 128;
    const int nBase = blockIdx.y * 128;
    const int tid = threadIdx.x;
    const int lane = tid & 63;
    const int wave = tid >> 6;
    const int wm = wave >> 1, wn = wave & 1;
    const int cq = lane & 15, quad = lane >> 4;

    __shared__ __align__(16) short As[128 * 64];
    __shared__ __align__(16) short Bs[128 * 64];

    const short* Ag = Ag0 + (size_t)mBase * H_DIM;
    const short* Bg = Bg0 + ((size_t)e * TWO_D + nBase) * H_DIM;

    f4v acc[4][4];
    #pragma unroll
    for (int mt = 0; mt < 4; ++mt)
        #pragma unroll
        for (int nt = 0; nt < 4; ++nt)
            acc[mt][nt] = (f4v){0.f, 0.f, 0.f, 0.f};

    const int srow8 = lane >> 3;                 // 0..7
    const int gco = ((lane & 7) ^ srow8) * 8;    // swizzled global k-offset (elements)
    const int cq7 = cq & 7;

    for (int k0 = 0; k0 < H_DIM; k0 += 64) {
        #pragma unroll
        for (int i = 0; i < 4; ++i) {
            const int r = wave * 32 + i * 8 + srow8;
            g2l16(Ag + (size_t)r * H_DIM + k0 + gco, As + (wave * 32 + i * 8) * 64);
            g2l16(Bg + (size_t)r * H_DIM + k0 + gco, Bs + (wave * 32 + i * 8) * 64);
        }
        __syncthreads();
        #pragma unroll
        for (int h = 0; h < 2; ++h) {
            s8v af[4], bf[4];
            const int pc = (((h << 2) + quad) ^ cq7) * 8;  // phys chunk offset (elements)
            #pragma unroll
            for (int i = 0; i < 4; ++i) {
                af[i] = *(const s8v*)(As + (wm * 64 + i * 16 + cq) * 64 + pc);
                bf[i] = *(const s8v*)(Bs + (wn * 64 + i * 16 + cq) * 64 + pc);
            }
            #pragma unroll
            for (int mt = 0; mt < 4; ++mt)
                #pragma unroll
                for (int nt = 0; nt < 4; ++nt)
                    acc[mt][nt] = __builtin_amdgcn_mfma_f32_16x16x32_bf16(
                        af[mt], bf[nt], acc[mt][nt], 0, 0, 0);
        }
        __syncthreads();
    }

    // epilogue: even nt tile = gate, odd nt tile = up for the same D-cols.
    float rwv[4][4];
    #pragma unroll
    for (int mt = 0; mt < 4; ++mt)
        #pragma unroll
        for (int r = 0; r < 4; ++r)
            rwv[mt][r] = rw[(size_t)(mBase + wm * 64 + mt * 16 + quad * 4 + r) * E_DIM + e];

    #pragma unroll
    for (int p = 0; p < 2; ++p) {
        const int j = (((nBase + wn * 64 + p * 32) >> 5) << 4) + cq;   // D-col in [0,1024)
        const float gb = b1[(size_t)e * TWO_D + 2 * j];
        const float ub = b1[(size_t)e * TWO_D + 2 * j + 1];
        #pragma unroll
        for (int mt = 0; mt < 4; ++mt) {
            #pragma unroll
            for (int r = 0; r < 4; ++r) {
                float gate = acc[mt][2 * p][r] + gb;
                float up   = acc[mt][2 * p + 1][r] + ub;
                gate = fminf(gate, LIMIT_C);
                up = fminf(fmaxf(up, -LIMIT_C), LIMIT_C);
                float glu = gate / (1.f + __expf(-ALPHA_C * gate));
                float a = (up + 1.f) * glu * rwv[mt][r];
                const int row = mBase + wm * 64 + mt * 16 + quad * 4 + r;
                act2[(size_t)row * K2 + (size_t)e * D_DIM + j] = __float2bfloat16(a);
            }
        }
    }
}

// ---------------- GEMM2 single-pass, 2-phase pipelined, XCD m-grouping ----------------
// out = act2 @ w3b^T + sum_e rw*b3. A: act2 [T][8192] bf16 (128 MB, L3-resident).
// B: w3b [H][8192] bf16. K=8192, 128 BK=64 steps. Grid 512 = 2/CU.
// id mapping: m = id&63 (fastest), n = id>>6. The 8 sharers of one A m-panel are
// ids {m, m+64, ..., m+448} -> identical id%8 -> SAME XCD (round-robin dispatch):
// each A-panel is fetched from L3 once per XCD and re-served from that XCD's L2,
// cutting L3-side reads 4x (1 GB -> 256 MB) vs the old n=id&7 mapping where the 8
// sharers sat on 8 different XCDs. Blocks id and id+256 (the two residents of a CU)
// share the same m -> same A-panel in L1/L2. k-synchronized sliding window keeps
// the per-XCD L2 working set ~256 KB.

#define FEN asm volatile("" ::: "memory")
#define BARR { FEN; __builtin_amdgcn_s_barrier(); FEN; }
#define VMW0 asm volatile("s_waitcnt vmcnt(0)" ::: "memory")

__global__ __launch_bounds__(256, 2) void gemm2_kernel(
    const short* __restrict__ Ag0,     // act2
    const short* __restrict__ Bg0,     // w3b
    const float* __restrict__ rw,      // [T][E]
    const float* __restrict__ b3,      // [E][H]
    float* __restrict__ out)           // [T][H]
{
    const int id = blockIdx.x;
    const int mBase = (id & 63) * 128;
    const int nBase = (id >> 6) * 128;
    const int tid = threadIdx.x;
    const int lane = tid & 63;
    const int wave = tid >> 6;
    const int wm = wave >> 1, wn = wave & 1;
    const int cq = lane & 15, quad = lane >> 4;

    __shared__ __align__(16) short As[2][128 * 64];   // 32 KiB
    __shared__ __align__(16) short Bs[2][128 * 64];   // 32 KiB

    const short* Ag = Ag0 + (size_t)mBase * K2;
    const short* Bg = Bg0 + (size_t)nBase * K2;

    f4v acc[4][4];
    #pragma unroll
    for (int mt = 0; mt < 4; ++mt)
        #pragma unroll
        for (int nt = 0; nt < 4; ++nt)
            acc[mt][nt] = (f4v){0.f, 0.f, 0.f, 0.f};

    const int srow8 = lane >> 3;
    const int gco = ((lane & 7) ^ srow8) * 8;
    const int cq7 = cq & 7;

    // prologue: stage tile 0, wait, barrier
    #pragma unroll
    for (int i = 0; i < 4; ++i) {
        const int r = wave * 32 + i * 8 + srow8;
        g2l16(Ag + (size_t)r * K2 + 0 + gco, &As[0][(wave * 32 + i * 8) * 64]);
        g2l16(Bg + (size_t)r * K2 + 0 + gco, &Bs[0][(wave * 32 + i * 8) * 64]);
    }
    VMW0;
    BARR;

    int cur = 0;
    #pragma unroll 1
    for (int k0 = 0; k0 < K2; k0 += 64) {
        // issue next tile's stages first (latency hides under this tile's compute)
        if (k0 + 64 < K2) {
            #pragma unroll
            for (int i = 0; i < 4; ++i) {
                const int r = wave * 32 + i * 8 + srow8;
                g2l16(Ag + (size_t)r * K2 + k0 + 64 + gco,
                      &As[cur ^ 1][(wave * 32 + i * 8) * 64]);
                g2l16(Bg + (size_t)r * K2 + k0 + 64 + gco,
                      &Bs[cur ^ 1][(wave * 32 + i * 8) * 64]);
            }
        }
        FEN;  // keep stages issued before the compute phase
        const short* Ab = As[cur];
        const short* Bb = Bs[cur];
        __builtin_amdgcn_s_setprio(1);
        #pragma unroll
        for (int h = 0; h < 2; ++h) {
            s8v af[4], bf[4];
            const int pc = (((h << 2) + quad) ^ cq7) * 8;
            #pragma unroll
            for (int i = 0; i < 4; ++i) {
                af[i] = *(const s8v*)(Ab + (wm * 64 + i * 16 + cq) * 64 + pc);
                bf[i] = *(const s8v*)(Bb + (wn * 64 + i * 16 + cq) * 64 + pc);
            }
            #pragma unroll
            for (int mt = 0; mt < 4; ++mt)
                #pragma unroll
                for (int nt = 0; nt < 4; ++nt)
                    acc[mt][nt] = __builtin_amdgcn_mfma_f32_16x16x32_bf16(
                        af[mt], bf[nt], acc[mt][nt], 0, 0, 0);
        }
        __builtin_amdgcn_s_setprio(0);
        VMW0;   // staged tile t+1 fully landed
        BARR;   // all waves done reading buf[cur] and staging
        cur ^= 1;
    }

    // epilogue: out = acc + sum_e rw[row][e] * b3[e][col]
    #pragma unroll
    for (int mt = 0; mt < 4; ++mt) {
        #pragma unroll
        for (int r = 0; r < 4; ++r) {
            const int row = mBase + wm * 64 + mt * 16 + quad * 4 + r;
            const float4 rwa = *(const float4*)(rw + (size_t)row * E_DIM);
            const float4 rwb = *(const float4*)(rw + (size_t)row * E_DIM + 4);
            #pragma unroll
            for (int nt = 0; nt < 4; ++nt) {
                const int col = nBase + wn * 64 + nt * 16 + cq;
                float bias = rwa.x * b3[0 * H_DIM + col] + rwa.y * b3[1 * H_DIM + col]
                           + rwa.z * b3[2 * H_DIM + col] + rwa.w * b3[3 * H_DIM + col]
                           + rwb.x * b3[4 * H_DIM + col] + rwb.y * b3[5 * H_DIM + col]
                           + rwb.z * b3[6 * H_DIM + col] + rwb.w * b3[7 * H_DIM + col];
                out[(size_t)row * H_DIM + col] = acc[mt][nt][r] + bias;
            }
        }
    }
}

// ---------------- launch ----------------

extern "C" void kernel_launch(void* const* d_in, const int* in_sizes, int n_in,
                              void* d_out, int out_size, void* d_ws, size_t ws_size,
                              hipStream_t stream) {
    const float* hs = (const float*)d_in[0];   // [T,H]
    const float* rw = (const float*)d_in[1];   // [T,E]
    const float* w1 = (const float*)d_in[2];   // [E,H,2D]
    const float* b1 = (const float*)d_in[3];   // [E,2D]
    const float* w3 = (const float*)d_in[4];   // [E,D,H]
    const float* b3 = (const float*)d_in[5];   // [E,H]
    float* out = (float*)d_out;

    char* ws = (char*)d_ws;
    unsigned short* hsb  = (unsigned short*)(ws);                          // 16 MB
    unsigned short* w1b  = (unsigned short*)(ws + ((size_t)16 << 20));     // 32 MB
    unsigned short* w3b  = (unsigned short*)(ws + ((size_t)48 << 20));     // 16 MB
    unsigned short* act2 = (unsigned short*)(ws + ((size_t)64 << 20));     // 128 MB

    // 1) hs -> bf16
    {
        size_t n = (size_t)T_DIM * H_DIM;  // 8388608
        f32_to_bf16_kernel<<<dim3(n / (256 * 4)), dim3(256), 0, stream>>>(hs, hsb, n);
    }
    // 2) W1 [E][H][2D] -> w1b [E][2D'][H] bf16 with gate/up 16-col deinterleave
    transpose_conv_kernel<<<dim3(TWO_D / 32, H_DIM / 32, E_DIM), dim3(256), 0, stream>>>(
        w1, w1b, TWO_D, (size_t)H_DIM * TWO_D, (size_t)TWO_D * H_DIM, (size_t)H_DIM, 1);
    // 3) W3 [E][D][H] -> w3b [H][E*D] bf16  (out idx = b*D + c*(E*D) + r)
    transpose_conv_kernel<<<dim3(H_DIM / 32, D_DIM / 32, E_DIM), dim3(256), 0, stream>>>(
        w3, w3b, H_DIM, (size_t)D_DIM * H_DIM, (size_t)D_DIM, (size_t)K2, 0);
    // 4) GEMM1 + GLU epilogue -> act2  (x=m fastest for XCD B-sharing)
    gemm1_kernel<<<dim3(T_DIM / 128, TWO_D / 128, E_DIM), dim3(256), 0, stream>>>(
        (const short*)hsb, (const short*)w1b, b1, rw, (__hip_bfloat16*)act2);
    // 5) GEMM2 single-pass 2-phase, XCD m-grouped (512 blocks = 2/CU) -> out
    gemm2_kernel<<<dim3(512), dim3(256), 0, stream>>>(
        (const short*)act2, (const short*)w3b, rw, b3, out);
}